// Round 22
// baseline (1943.132 us; speedup 1.0000x reference)
//
#include <hip/hip_runtime.h>

typedef __bf16 bf16;
typedef bf16 bf16x8 __attribute__((ext_vector_type(8)));
typedef float f32x4 __attribute__((ext_vector_type(4)));

#define SQ  1024
#define DIM 768
#define NH  12
#define NL  12
#define F4  3072
#define NPADV 50304   // 50257 padded to 128
#define NVOC  50257

// ---- async global->LDS 16B (dst = wave-uniform base + lane*16) ----
__device__ __forceinline__ void async16(bf16* lds, const bf16* g) {
  __builtin_amdgcn_global_load_lds(
      (const __attribute__((address_space(1))) unsigned int*)g,
      (__attribute__((address_space(3))) unsigned int*)lds, 16, 0, 0);
}

// ---------------- embedding ----------------
__global__ __launch_bounds__(256) void embed_kernel(
    const int* __restrict__ tokens, const float* __restrict__ tok_emb,
    const float* __restrict__ pos_emb, float* __restrict__ x) {
  int row = blockIdx.x;
  int s   = row & (SQ - 1);
  int tok = tokens[row];
  for (int i = threadIdx.x; i < DIM; i += 256)
    x[(size_t)row * DIM + i] = tok_emb[(size_t)tok * DIM + i] + pos_emb[(size_t)s * DIM + i];
}

// ---------------- LayerNorm ----------------
__global__ __launch_bounds__(256) void ln_kernel(
    const float* __restrict__ x, const float* __restrict__ g,
    const float* __restrict__ b, bf16* __restrict__ out) {
  int row = blockIdx.x;
  const float* xr = x + (size_t)row * DIM;
  int t = threadIdx.x;
  float v0 = xr[t], v1 = xr[t + 256], v2 = xr[t + 512];
  float s  = v0 + v1 + v2;
  float sq = v0 * v0 + v1 * v1 + v2 * v2;
#pragma unroll
  for (int off = 32; off; off >>= 1) {
    s  += __shfl_xor(s, off);
    sq += __shfl_xor(sq, off);
  }
  __shared__ float rs[4], rq[4];
  int wid = t >> 6, lane = t & 63;
  if (lane == 0) { rs[wid] = s; rq[wid] = sq; }
  __syncthreads();
  float S = rs[0] + rs[1] + rs[2] + rs[3];
  float Q = rq[0] + rq[1] + rq[2] + rq[3];
  float mean = S * (1.0f / DIM);
  float var  = Q * (1.0f / DIM) - mean * mean;
  float rstd = rsqrtf(var + 1e-5f);
  bf16* orow = out + (size_t)row * DIM;
  orow[t]       = (bf16)((v0 - mean) * rstd * g[t]       + b[t]);
  orow[t + 256] = (bf16)((v1 - mean) * rstd * g[t + 256] + b[t + 256]);
  orow[t + 512] = (bf16)((v2 - mean) * rstd * g[t + 512] + b[t + 512]);
}

// ---------------- batched transpose-convert: f32 [K,N] -> bf16 [Npad,K] ----
__global__ __launch_bounds__(256) void tconv_kernel(
    const float* __restrict__ src, bf16* __restrict__ dst,
    int K, int N, size_t s_stride, size_t d_stride) {
  __shared__ float tile[32][33];
  const float* s = src + blockIdx.z * s_stride;
  bf16* d = dst + blockIdx.z * d_stride;
  int n0 = blockIdx.x * 32, k0 = blockIdx.y * 32;
  int tx = threadIdx.x & 31, ty = threadIdx.x >> 5;
#pragma unroll
  for (int r = 0; r < 32; r += 8) {
    int n = n0 + tx;
    tile[ty + r][tx] = (n < N) ? s[(size_t)(k0 + ty + r) * N + n] : 0.f;
  }
  __syncthreads();
#pragma unroll
  for (int r = 0; r < 32; r += 8)
    d[(size_t)(n0 + ty + r) * K + k0 + tx] = (bf16)tile[tx][ty + r];
}

// ---------------- pack qkv bias ----------------
__global__ __launch_bounds__(256) void packb_kernel(
    const float* __restrict__ bq, const float* __restrict__ bk,
    const float* __restrict__ bv, float* __restrict__ qkvb) {
  int l = blockIdx.x, t = threadIdx.x;
  for (int i = t; i < DIM; i += 256) {
    qkvb[(size_t)l * 2304 + i]        = bq[(size_t)l * DIM + i];
    qkvb[(size_t)l * 2304 + 768 + i]  = bk[(size_t)l * DIM + i];
    qkvb[(size_t)l * 2304 + 1536 + i] = bv[(size_t)l * DIM + i];
  }
}

// ---------------- MFMA GEMM: DEPTH-deep dbuf + counted vmcnt + swizzles ----
// A: bf16 [M,K] rm. BT: bf16 [Npad,K] rm. BN = 128.
// BM=128: 8 waves. BM=64: 4 waves. Wave tile 32x64. XCD remap (nwg%8==0).
// NT: non-temporal f32 output via LDS-transposed dwordx4 epilogue (head).
template <int BM, int DEPTH, bool GELU_, bool RESID, bool OUTBF, bool NT>
__global__ __launch_bounds__(BM == 128 ? 512 : 256) void gemm_bt(
    const bf16* __restrict__ A, const bf16* __restrict__ BT,
    const float* __restrict__ bias, const float* __restrict__ resid,
    float* __restrict__ outF, bf16* __restrict__ outB,
    int M, int N, int K) {
  constexpr int BK = 64;
  constexpr int WAVES = (BM == 128) ? 8 : 4;
  constexpr int BROW = 128 / WAVES;          // B rows staged per wave
  constexpr int NB = BROW / 8;               // B async16 per wave
  constexpr int EPLD = 68;                   // epilogue LDS row stride (dwords)
  constexpr size_t GBYTES = (size_t)DEPTH * (BM + 128) * BK * 2;
  constexpr size_t EBYTES = NT ? (size_t)WAVES * 32 * EPLD * 4 : 0;
  constexpr size_t SBYTES = (EBYTES > GBYTES) ? EBYTES : GBYTES;
  __shared__ __align__(16) char smem[SBYTES];

  // ---- bijective XCD swizzle: XCD (lid%8) owns contiguous m-fast chunk ----
  const int gx = gridDim.x;
  const int lid = blockIdx.y * gx + blockIdx.x;
  const int q8 = (gx * gridDim.y) >> 3;
  const int work = (lid & 7) * q8 + (lid >> 3);
  const int m0 = (work % gx) * BM, n0 = (work / gx) * 128;

  const int t = threadIdx.x, w = t >> 6, lane = t & 63;
  const int wm = (w >> 1) * 32, wn = (w & 1) * 64;
  const int row16 = lane & 15, kg = lane >> 4;
  const int srow = lane >> 3;
  const int scol = ((lane & 7) ^ srow) * 8;  // pre-swizzled source col
  f32x4 acc[2][4] = {};

  const bf16* Abase = A  + (size_t)(m0 + w * 16 + srow) * K + scol;
  const bf16* Bbase = BT + (size_t)(n0 + w * BROW + srow) * K + scol;

  auto stage = [&](int buf, int k0) {
    bf16* as = (bf16*)smem + (size_t)buf * BM * BK;
    bf16* bs = (bf16*)smem + (size_t)DEPTH * BM * BK + (size_t)buf * 128 * BK;
#pragma unroll
    for (int i = 0; i < 2; i++)
      async16(as + (w * 16 + i * 8) * BK, Abase + (size_t)(i * 8) * K + k0);
#pragma unroll
    for (int i = 0; i < NB; i++)
      async16(bs + (w * BROW + i * 8) * BK, Bbase + (size_t)(i * 8) * K + k0);
  };

  const int nk = K / BK;
  stage(0, 0);
  if constexpr (DEPTH == 3) stage(1, BK);
  for (int ki = 0; ki < nk; ki++) {
    const int cur = ki % DEPTH;
    const bf16* Ac = (const bf16*)smem + (size_t)cur * BM * BK;
    const bf16* Bc = (const bf16*)smem + (size_t)DEPTH * BM * BK + (size_t)cur * 128 * BK;
    if (ki + DEPTH - 1 < nk) {
      stage((ki + DEPTH - 1) % DEPTH, (ki + DEPTH - 1) * BK);
      if constexpr (DEPTH == 3)      asm volatile("s_waitcnt vmcnt(12)" ::: "memory");
      else if constexpr (BM == 128)  asm volatile("s_waitcnt vmcnt(4)"  ::: "memory");
      else                           asm volatile("s_waitcnt vmcnt(6)"  ::: "memory");
    } else if (DEPTH == 3 && ki + 2 == nk) {
      asm volatile("s_waitcnt vmcnt(6)" ::: "memory");
    } else {
      asm volatile("s_waitcnt vmcnt(0)" ::: "memory");
    }
    __builtin_amdgcn_s_barrier();
    __builtin_amdgcn_sched_barrier(0);
    const int psw = row16 & 7;
#pragma unroll
    for (int kk = 0; kk < 2; kk++) {
      const int pc = ((kk * 4 + kg) ^ psw) * 8;           // swizzled read col
      bf16x8 af[2], bfv[4];
#pragma unroll
      for (int i = 0; i < 2; i++)
        af[i] = *(const bf16x8*)(&Ac[(wm + i * 16 + row16) * BK + pc]);
#pragma unroll
      for (int j = 0; j < 4; j++)
        bfv[j] = *(const bf16x8*)(&Bc[(wn + j * 16 + row16) * BK + pc]);
#pragma unroll
      for (int i = 0; i < 2; i++)
#pragma unroll
        for (int j = 0; j < 4; j++)
          acc[i][j] = __builtin_amdgcn_mfma_f32_16x16x32_bf16(af[i], bfv[j], acc[i][j], 0, 0, 0);
    }
    if (ki + 1 < nk) {
      __builtin_amdgcn_s_barrier();
      __builtin_amdgcn_sched_barrier(0);
    }
  }

  if constexpr (NT) {
    // ---- LDS-transposed NT epilogue: 256B-contiguous dwordx4 stores ----
    __syncthreads();
    float* ws = (float*)smem + (size_t)w * 32 * EPLD;
#pragma unroll
    for (int i = 0; i < 2; i++)
#pragma unroll
      for (int j = 0; j < 4; j++) {
        int col = n0 + wn + j * 16 + row16;
        float bi = (col < N) ? bias[col] : 0.f;
#pragma unroll
        for (int r = 0; r < 4; r++)
          ws[(i * 16 + kg * 4 + r) * EPLD + j * 16 + row16] = acc[i][j][r] + bi;
      }
    const int lr = lane >> 4, lc = (lane & 15) * 4;
#pragma unroll
    for (int p = 0; p < 8; p++) {
      int row = m0 + (w >> 1) * 32 + p * 4 + lr;
      int col = n0 + (w & 1) * 64 + lc;
      f32x4 v = *(const f32x4*)&ws[(p * 4 + lr) * EPLD + lc];
      float* dst = outF + (size_t)row * N + col;
      if (col + 3 < N) {
        __builtin_nontemporal_store(v, (f32x4*)dst);
      } else {
#pragma unroll
        for (int e = 0; e < 4; e++)
          if (col + e < N) __builtin_nontemporal_store(v[e], dst + e);
      }
    }
  } else {
#pragma unroll
    for (int i = 0; i < 2; i++)
#pragma unroll
      for (int j = 0; j < 4; j++) {
        int col = n0 + wn + j * 16 + row16;
        if (col < N) {
          float bi = bias[col];
#pragma unroll
          for (int r = 0; r < 4; r++) {
            int row = m0 + wm + i * 16 + kg * 4 + r;
            float val = acc[i][j][r] + bi;
            if constexpr (GELU_) val = 0.5f * val * (1.0f + erff(val * 0.70710678f));
            if constexpr (RESID) val += resid[(size_t)row * N + col];
            if constexpr (OUTBF) outB[(size_t)row * N + col] = (bf16)val;
            else                 outF[(size_t)row * N + col] = val;
          }
        }
      }
  }
}

// ---------------- flash attention: 64 q-rows/block, 4 waves, KVBLK=128 -----
__global__ __launch_bounds__(256) void fattn_kernel(
    const bf16* __restrict__ qkv, bf16* __restrict__ o) {
  constexpr int LP  = 72;    // Ks row stride (d-dim 64 + 8)
  constexpr int LPV = 136;   // Vt row stride (key-dim 128 + 8)
  constexpr int LPP = 136;   // Ps row stride (key-dim 128 + 8)
  constexpr int LDQ = 2304;
  __shared__ bf16 Ks[128 * LP];
  __shared__ bf16 Vt[64 * LPV];
  __shared__ bf16 Ps[4][16 * LPP];

  const int qt = 15 - (blockIdx.x & 15);        // descending work order
  const int hb = blockIdx.x >> 4;
  const int h  = hb % NH;
  const int b  = hb / NH;
  const int t = threadIdx.x;
  const int w = t >> 6, lane = t & 63;
  const int row16 = lane & 15, kg = lane >> 4;

  const bf16* kbase = qkv + 768  + (size_t)(b * SQ) * LDQ + h * 64;
  const bf16* vbase = qkv + 1536 + (size_t)(b * SQ) * LDQ + h * 64;

  const int wq0  = qt * 64 + w * 16;
  const int qrow = wq0 + row16;
  const bf16* qptr = qkv + (size_t)(b * SQ + qrow) * LDQ + h * 64;
  const bf16x8 qf0 = *(const bf16x8*)(qptr + kg * 8);
  const bf16x8 qf1 = *(const bf16x8*)(qptr + 32 + kg * 8);

  f32x4 oacc[4] = {};
  float mrow[4] = {-1e30f, -1e30f, -1e30f, -1e30f};
  float lrow[4] = {0.f, 0.f, 0.f, 0.f};
  const int myq = wq0 + kg * 4;
  const int ntiles = qt / 2 + 1;

  for (int jb0 = 0; jb0 < ntiles; jb0++) {
    const int j0 = jb0 * 128;
    __syncthreads();
#pragma unroll
    for (int it = 0; it < 4; it++) {
      int idx = t + it * 256;
      int key = idx >> 3, d8 = (idx & 7) * 8;
      *(uint4*)(&Ks[key * LP + d8]) =
          *(const uint4*)(kbase + (size_t)(j0 + key) * LDQ + d8);
      bf16x8 vv = *(const bf16x8*)(vbase + (size_t)(j0 + key) * LDQ + d8);
      int kc = key >> 3, kl = key & 7;
#pragma unroll
      for (int e = 0; e < 8; e++) {
        int d = d8 + e;
        Vt[d * LPV + ((kc ^ (d >> 3)) << 3) + kl] = vv[e];
      }
    }
    __syncthreads();

    f32x4 sacc[8];
    __builtin_amdgcn_s_setprio(1);
#pragma unroll
    for (int jb = 0; jb < 8; jb++) {
      bf16x8 kf0 = *(const bf16x8*)(&Ks[(jb * 16 + row16) * LP + kg * 8]);
      bf16x8 kf1 = *(const bf16x8*)(&Ks[(jb * 16 + row16) * LP + 32 + kg * 8]);
      f32x4 sa = {};
      sa = __builtin_amdgcn_mfma_f32_16x16x32_bf16(qf0, kf0, sa, 0, 0, 0);
      sa = __builtin_amdgcn_mfma_f32_16x16x32_bf16(qf1, kf1, sa, 0, 0, 0);
      sacc[jb] = sa;
    }
    __builtin_amdgcn_s_setprio(0);

    constexpr float SC = 0.125f * 1.44269504f;
    if (j0 + 127 > wq0) {
#pragma unroll
      for (int jb = 0; jb < 8; jb++) {
        int keyg = j0 + jb * 16 + row16;
#pragma unroll
        for (int r = 0; r < 4; r++)
          sacc[jb][r] = (keyg <= myq + r) ? sacc[jb][r] * SC : -1e30f;
      }
    } else {
#pragma unroll
      for (int jb = 0; jb < 8; jb++)
#pragma unroll
        for (int r = 0; r < 4; r++)
          sacc[jb][r] *= SC;
    }

    float p[8][4];
#pragma unroll
    for (int r = 0; r < 4; r++) {
      float mx = sacc[0][r];
#pragma unroll
      for (int jb = 1; jb < 8; jb++) mx = fmaxf(mx, sacc[jb][r]);
      mx = fmaxf(mx, __shfl_xor(mx, 1));
      mx = fmaxf(mx, __shfl_xor(mx, 2));
      mx = fmaxf(mx, __shfl_xor(mx, 4));
      mx = fmaxf(mx, __shfl_xor(mx, 8));
      float mn = fmaxf(mrow[r], mx);
      float al = exp2f(mrow[r] - mn);
      mrow[r] = mn;
      float ls = 0.f;
#pragma unroll
      for (int jb = 0; jb < 8; jb++) {
        float pv = exp2f(sacc[jb][r] - mn);
        p[jb][r] = pv;
        ls += pv;
      }
      ls += __shfl_xor(ls, 1);
      ls += __shfl_xor(ls, 2);
      ls += __shfl_xor(ls, 4);
      ls += __shfl_xor(ls, 8);
      lrow[r] = lrow[r] * al + ls;
#pragma unroll
      for (int dt = 0; dt < 4; dt++) oacc[dt][r] *= al;
    }

    bf16* pw = &Ps[w][0];
#pragma unroll
    for (int jb = 0; jb < 8; jb++)
#pragma unroll
      for (int r = 0; r < 4; r++)
        pw[(kg * 4 + r) * LPP + jb * 16 + row16] = (bf16)p[jb][r];

    bf16x8 pf[4];
#pragma unroll
    for (int m = 0; m < 4; m++)
      pf[m] = *(const bf16x8*)(&pw[row16 * LPP + m * 32 + kg * 8]);

    __builtin_amdgcn_s_setprio(1);
#pragma unroll
    for (int dt = 0; dt < 4; dt++) {
      int drow = dt * 16 + row16;
      int sw = drow >> 3;
#pragma unroll
      for (int m = 0; m < 4; m++) {
        bf16x8 vf = *(const bf16x8*)(&Vt[drow * LPV + (((m * 4 + kg) ^ sw) << 3)]);
        oacc[dt] = __builtin_amdgcn_mfma_f32_16x16x32_bf16(pf[m], vf, oacc[dt], 0, 0, 0);
      }
    }
    __builtin_amdgcn_s_setprio(0);
  }

  bf16* obase = o + (size_t)(b * SQ + wq0 + kg * 4) * DIM + h * 64;
#pragma unroll
  for (int r = 0; r < 4; r++) {
    float inv = 1.0f / lrow[r];
#pragma unroll
    for (int dt = 0; dt < 4; dt++)
      obase[(size_t)r * DIM + dt * 16 + row16] = (bf16)(oacc[dt][r] * inv);
  }
}

// ---------------------------------------------------------------------------
extern "C" void kernel_launch(void* const* d_in, const int* in_sizes, int n_in,
                              void* d_out, int out_size, void* d_ws, size_t ws_size,
                              hipStream_t stream) {
  const int*   tokens  = (const int*)  d_in[0];
  const float* tok_emb = (const float*)d_in[1];
  const float* pos_emb = (const float*)d_in[2];
  const float* ln1_g   = (const float*)d_in[3];
  const float* ln1_b   = (const float*)d_in[4];
  const float* wq      = (const float*)d_in[5];
  const float* bq      = (const float*)d_in[6];
  const float* wk      = (const float*)d_in[7];
  const float* bk      = (const float*)d_in[8];
  const float* wv      = (const float*)d_in[9];
  const float* bv      = (const float*)d_in[10];
  const float* wo      = (const float*)d_in[11];
  const float* bo      = (const float*)d_in[12];
  const float* ln2_g   = (const float*)d_in[13];
  const float* ln2_b   = (const float*)d_in[14];
  const float* w1      = (const float*)d_in[15];
  const float* b1      = (const float*)d_in[16];
  const float* w2      = (const float*)d_in[17];
  const float* b2      = (const float*)d_in[18];
  const float* fn_g    = (const float*)d_in[19];
  const float* fn_b    = (const float*)d_in[20];
  const float* head_w  = (const float*)d_in[21];
  const float* head_b  = (const float*)d_in[22];
  float* out = (float*)d_out;

  const int ROWS = 2 * SQ;  // 2048
  char* p = (char*)d_ws;
  float* x   = (float*)p;  p += (size_t)ROWS * DIM * 4;
  bf16*  h   = (bf16*)p;   p += (size_t)ROWS * DIM * 2;
  bf16*  qkv = (bf16*)p;   p += (size_t)ROWS * 2304 * 2;
  bf16*  ao  = (bf16*)p;   p += (size_t)ROWS * DIM * 2;
  bf16*  mid = (bf16*)p;   p += (size_t)ROWS * F4  * 2;
  bf16*  WqkvT = (bf16*)p; p += (size_t)NL * 2304 * DIM * 2;
  bf16*  WoT   = (bf16*)p; p += (size_t)NL * DIM * DIM * 2;
  bf16*  W1T   = (bf16*)p; p += (size_t)NL * F4 * DIM * 2;
  bf16*  W2T   = (bf16*)p; p += (size_t)NL * DIM * F4 * 2;
  bf16*  WhT   = (bf16*)p; p += (size_t)NPADV * DIM * 2;
  float* qkvb  = (float*)p; p += (size_t)NL * 2304 * 4;

  embed_kernel<<<ROWS, 256, 0, stream>>>(tokens, tok_emb, pos_emb, x);

  {
    dim3 gdd(DIM / 32, DIM / 32, NL);
    size_t ss = (size_t)DIM * DIM, ds = (size_t)2304 * DIM;
    tconv_kernel<<<gdd, 256, 0, stream>>>(wq, WqkvT,                       DIM, DIM, ss, ds);
    tconv_kernel<<<gdd, 256, 0, stream>>>(wk, WqkvT + (size_t)768  * DIM,  DIM, DIM, ss, ds);
    tconv_kernel<<<gdd, 256, 0, stream>>>(wv, WqkvT + (size_t)1536 * DIM,  DIM, DIM, ss, ds);
    tconv_kernel<<<gdd, 256, 0, stream>>>(wo, WoT, DIM, DIM, ss, ss);
    dim3 g1(F4 / 32, DIM / 32, NL);
    tconv_kernel<<<g1, 256, 0, stream>>>(w1, W1T, DIM, F4, (size_t)DIM * F4, (size_t)F4 * DIM);
    dim3 g2(DIM / 32, F4 / 32, NL);
    tconv_kernel<<<g2, 256, 0, stream>>>(w2, W2T, F4, DIM, (size_t)F4 * DIM, (size_t)DIM * F4);
    dim3 gh(NPADV / 32, DIM / 32, 1);
    tconv_kernel<<<gh, 256, 0, stream>>>(head_w, WhT, DIM, NVOC, 0, 0);
    packb_kernel<<<NL, 256, 0, stream>>>(bq, bk, bv, qkvb);
  }

  dim3 gQKV(32, 2304 / 128);   // 576
  dim3 gD(32, DIM / 128);      // 192
  dim3 gF(32, F4 / 128);       // 768
  dim3 gV64(32, NPADV / 128);  // 12576 (BM=64 head: 3 blocks/CU)

  for (int l = 0; l < NL; l++) {
    ln_kernel<<<ROWS, 256, 0, stream>>>(x, ln1_g + l * DIM, ln1_b + l * DIM, h);
    gemm_bt<64, 2, false, false, true, false><<<gQKV, 256, 0, stream>>>(
        h, WqkvT + (size_t)l * 2304 * DIM, qkvb + (size_t)l * 2304,
        nullptr, nullptr, qkv, ROWS, 2304, DIM);
    fattn_kernel<<<2 * NH * (SQ / 64), 256, 0, stream>>>(qkv, ao);
    gemm_bt<64, 3, false, true, false, false><<<gD, 256, 0, stream>>>(
        ao, WoT + (size_t)l * DIM * DIM, bo + l * DIM, x, x, nullptr, ROWS, DIM, DIM);
    ln_kernel<<<ROWS, 256, 0, stream>>>(x, ln2_g + l * DIM, ln2_b + l * DIM, h);
    gemm_bt<64, 2, true, false, true, false><<<gF, 256, 0, stream>>>(
        h, W1T + (size_t)l * F4 * DIM, b1 + l * F4, nullptr, nullptr, mid, ROWS, F4, DIM);
    gemm_bt<64, 3, false, true, false, false><<<gD, 256, 0, stream>>>(
        mid, W2T + (size_t)l * DIM * F4, b2 + l * DIM, x, x, nullptr, ROWS, DIM, F4);
  }
  ln_kernel<<<ROWS, 256, 0, stream>>>(x, fn_g, fn_b, h);
  // head: BM=64 4-wave (48KB LDS -> 3 blocks/CU) + NT epilogue
  gemm_bt<64, 2, false, false, false, true><<<gV64, 256, 0, stream>>>(
      h, WhT, head_b, nullptr, out, nullptr, ROWS, NVOC, DIM);
}

// Round 23
// 1882.092 us; speedup vs baseline: 1.0324x; 1.0324x over previous
//
#include <hip/hip_runtime.h>

typedef __bf16 bf16;
typedef bf16 bf16x8 __attribute__((ext_vector_type(8)));
typedef float f32x4 __attribute__((ext_vector_type(4)));

#define SQ  1024
#define DIM 768
#define NH  12
#define NL  12
#define F4  3072
#define NPADV 50304   // 50257 padded to 128
#define NVOC  50257

// ---- async global->LDS 16B (dst = wave-uniform base + lane*16) ----
__device__ __forceinline__ void async16(bf16* lds, const bf16* g) {
  __builtin_amdgcn_global_load_lds(
      (const __attribute__((address_space(1))) unsigned int*)g,
      (__attribute__((address_space(3))) unsigned int*)lds, 16, 0, 0);
}

// ---------------- embedding ----------------
__global__ __launch_bounds__(256) void embed_kernel(
    const int* __restrict__ tokens, const float* __restrict__ tok_emb,
    const float* __restrict__ pos_emb, float* __restrict__ x) {
  int row = blockIdx.x;
  int s   = row & (SQ - 1);
  int tok = tokens[row];
  for (int i = threadIdx.x; i < DIM; i += 256)
    x[(size_t)row * DIM + i] = tok_emb[(size_t)tok * DIM + i] + pos_emb[(size_t)s * DIM + i];
}

// ---------------- LayerNorm ----------------
__global__ __launch_bounds__(256) void ln_kernel(
    const float* __restrict__ x, const float* __restrict__ g,
    const float* __restrict__ b, bf16* __restrict__ out) {
  int row = blockIdx.x;
  const float* xr = x + (size_t)row * DIM;
  int t = threadIdx.x;
  float v0 = xr[t], v1 = xr[t + 256], v2 = xr[t + 512];
  float s  = v0 + v1 + v2;
  float sq = v0 * v0 + v1 * v1 + v2 * v2;
#pragma unroll
  for (int off = 32; off; off >>= 1) {
    s  += __shfl_xor(s, off);
    sq += __shfl_xor(sq, off);
  }
  __shared__ float rs[4], rq[4];
  int wid = t >> 6, lane = t & 63;
  if (lane == 0) { rs[wid] = s; rq[wid] = sq; }
  __syncthreads();
  float S = rs[0] + rs[1] + rs[2] + rs[3];
  float Q = rq[0] + rq[1] + rq[2] + rq[3];
  float mean = S * (1.0f / DIM);
  float var  = Q * (1.0f / DIM) - mean * mean;
  float rstd = rsqrtf(var + 1e-5f);
  bf16* orow = out + (size_t)row * DIM;
  orow[t]       = (bf16)((v0 - mean) * rstd * g[t]       + b[t]);
  orow[t + 256] = (bf16)((v1 - mean) * rstd * g[t + 256] + b[t + 256]);
  orow[t + 512] = (bf16)((v2 - mean) * rstd * g[t + 512] + b[t + 512]);
}

// ---------------- batched transpose-convert: f32 [K,N] -> bf16 [Npad,K] ----
__global__ __launch_bounds__(256) void tconv_kernel(
    const float* __restrict__ src, bf16* __restrict__ dst,
    int K, int N, size_t s_stride, size_t d_stride) {
  __shared__ float tile[32][33];
  const float* s = src + blockIdx.z * s_stride;
  bf16* d = dst + blockIdx.z * d_stride;
  int n0 = blockIdx.x * 32, k0 = blockIdx.y * 32;
  int tx = threadIdx.x & 31, ty = threadIdx.x >> 5;
#pragma unroll
  for (int r = 0; r < 32; r += 8) {
    int n = n0 + tx;
    tile[ty + r][tx] = (n < N) ? s[(size_t)(k0 + ty + r) * N + n] : 0.f;
  }
  __syncthreads();
#pragma unroll
  for (int r = 0; r < 32; r += 8)
    d[(size_t)(n0 + ty + r) * K + k0 + tx] = (bf16)tile[tx][ty + r];
}

// ---------------- pack qkv bias ----------------
__global__ __launch_bounds__(256) void packb_kernel(
    const float* __restrict__ bq, const float* __restrict__ bk,
    const float* __restrict__ bv, float* __restrict__ qkvb) {
  int l = blockIdx.x, t = threadIdx.x;
  for (int i = t; i < DIM; i += 256) {
    qkvb[(size_t)l * 2304 + i]        = bq[(size_t)l * DIM + i];
    qkvb[(size_t)l * 2304 + 768 + i]  = bk[(size_t)l * DIM + i];
    qkvb[(size_t)l * 2304 + 1536 + i] = bv[(size_t)l * DIM + i];
  }
}

// ---------------- MFMA GEMM: DEPTH-deep dbuf + counted vmcnt + swizzles ----
// A: bf16 [M,K] rm. BT: bf16 [Npad,K] rm. BN = 128.
// BM=128: 8 waves. BM=64: 4 waves. Wave tile 32x64. XCD remap (nwg%8==0).
// NT: non-temporal f32 output via LDS-transposed dwordx4 epilogue (head).
template <int BM, int DEPTH, bool GELU_, bool RESID, bool OUTBF, bool NT>
__global__ __launch_bounds__(BM == 128 ? 512 : 256) void gemm_bt(
    const bf16* __restrict__ A, const bf16* __restrict__ BT,
    const float* __restrict__ bias, const float* __restrict__ resid,
    float* __restrict__ outF, bf16* __restrict__ outB,
    int M, int N, int K) {
  constexpr int BK = 64;
  constexpr int WAVES = (BM == 128) ? 8 : 4;
  constexpr int BROW = 128 / WAVES;          // B rows staged per wave
  constexpr int NB = BROW / 8;               // B async16 per wave
  constexpr int EPLD = 68;                   // epilogue LDS row stride (dwords)
  constexpr size_t GBYTES = (size_t)DEPTH * (BM + 128) * BK * 2;
  constexpr size_t EBYTES = NT ? (size_t)WAVES * 32 * EPLD * 4 : 0;
  constexpr size_t SBYTES = (EBYTES > GBYTES) ? EBYTES : GBYTES;
  __shared__ __align__(16) char smem[SBYTES];

  // ---- bijective XCD swizzle: XCD (lid%8) owns contiguous m-fast chunk ----
  const int gx = gridDim.x;
  const int lid = blockIdx.y * gx + blockIdx.x;
  const int q8 = (gx * gridDim.y) >> 3;
  const int work = (lid & 7) * q8 + (lid >> 3);
  const int m0 = (work % gx) * BM, n0 = (work / gx) * 128;

  const int t = threadIdx.x, w = t >> 6, lane = t & 63;
  const int wm = (w >> 1) * 32, wn = (w & 1) * 64;
  const int row16 = lane & 15, kg = lane >> 4;
  const int srow = lane >> 3;
  const int scol = ((lane & 7) ^ srow) * 8;  // pre-swizzled source col
  f32x4 acc[2][4] = {};

  const bf16* Abase = A  + (size_t)(m0 + w * 16 + srow) * K + scol;
  const bf16* Bbase = BT + (size_t)(n0 + w * BROW + srow) * K + scol;

  auto stage = [&](int buf, int k0) {
    bf16* as = (bf16*)smem + (size_t)buf * BM * BK;
    bf16* bs = (bf16*)smem + (size_t)DEPTH * BM * BK + (size_t)buf * 128 * BK;
#pragma unroll
    for (int i = 0; i < 2; i++)
      async16(as + (w * 16 + i * 8) * BK, Abase + (size_t)(i * 8) * K + k0);
#pragma unroll
    for (int i = 0; i < NB; i++)
      async16(bs + (w * BROW + i * 8) * BK, Bbase + (size_t)(i * 8) * K + k0);
  };

  const int nk = K / BK;
  stage(0, 0);
  if constexpr (DEPTH == 3) stage(1, BK);
  for (int ki = 0; ki < nk; ki++) {
    const int cur = ki % DEPTH;
    const bf16* Ac = (const bf16*)smem + (size_t)cur * BM * BK;
    const bf16* Bc = (const bf16*)smem + (size_t)DEPTH * BM * BK + (size_t)cur * 128 * BK;
    if (ki + DEPTH - 1 < nk) {
      stage((ki + DEPTH - 1) % DEPTH, (ki + DEPTH - 1) * BK);
      if constexpr (DEPTH == 3)      asm volatile("s_waitcnt vmcnt(12)" ::: "memory");
      else if constexpr (BM == 128)  asm volatile("s_waitcnt vmcnt(4)"  ::: "memory");
      else                           asm volatile("s_waitcnt vmcnt(6)"  ::: "memory");
    } else if (DEPTH == 3 && ki + 2 == nk) {
      asm volatile("s_waitcnt vmcnt(6)" ::: "memory");
    } else {
      asm volatile("s_waitcnt vmcnt(0)" ::: "memory");
    }
    __builtin_amdgcn_s_barrier();
    __builtin_amdgcn_sched_barrier(0);
    const int psw = row16 & 7;
#pragma unroll
    for (int kk = 0; kk < 2; kk++) {
      const int pc = ((kk * 4 + kg) ^ psw) * 8;           // swizzled read col
      bf16x8 af[2], bfv[4];
#pragma unroll
      for (int i = 0; i < 2; i++)
        af[i] = *(const bf16x8*)(&Ac[(wm + i * 16 + row16) * BK + pc]);
#pragma unroll
      for (int j = 0; j < 4; j++)
        bfv[j] = *(const bf16x8*)(&Bc[(wn + j * 16 + row16) * BK + pc]);
#pragma unroll
      for (int i = 0; i < 2; i++)
#pragma unroll
        for (int j = 0; j < 4; j++)
          acc[i][j] = __builtin_amdgcn_mfma_f32_16x16x32_bf16(af[i], bfv[j], acc[i][j], 0, 0, 0);
    }
    if (ki + 1 < nk) {
      __builtin_amdgcn_s_barrier();
      __builtin_amdgcn_sched_barrier(0);
    }
  }

  if constexpr (NT) {
    // ---- LDS-transposed NT epilogue: 256B-contiguous dwordx4 stores ----
    __syncthreads();
    float* ws = (float*)smem + (size_t)w * 32 * EPLD;
#pragma unroll
    for (int i = 0; i < 2; i++)
#pragma unroll
      for (int j = 0; j < 4; j++) {
        int col = n0 + wn + j * 16 + row16;
        float bi = (col < N) ? bias[col] : 0.f;
#pragma unroll
        for (int r = 0; r < 4; r++)
          ws[(i * 16 + kg * 4 + r) * EPLD + j * 16 + row16] = acc[i][j][r] + bi;
      }
    const int lr = lane >> 4, lc = (lane & 15) * 4;
#pragma unroll
    for (int p = 0; p < 8; p++) {
      int row = m0 + (w >> 1) * 32 + p * 4 + lr;
      int col = n0 + (w & 1) * 64 + lc;
      f32x4 v = *(const f32x4*)&ws[(p * 4 + lr) * EPLD + lc];
      float* dst = outF + (size_t)row * N + col;
      if (col + 3 < N) {
        __builtin_nontemporal_store(v, (f32x4*)dst);
      } else {
#pragma unroll
        for (int e = 0; e < 4; e++)
          if (col + e < N) __builtin_nontemporal_store(v[e], dst + e);
      }
    }
  } else {
#pragma unroll
    for (int i = 0; i < 2; i++)
#pragma unroll
      for (int j = 0; j < 4; j++) {
        int col = n0 + wn + j * 16 + row16;
        if (col < N) {
          float bi = bias[col];
#pragma unroll
          for (int r = 0; r < 4; r++) {
            int row = m0 + wm + i * 16 + kg * 4 + r;
            float val = acc[i][j][r] + bi;
            if constexpr (GELU_) val = 0.5f * val * (1.0f + erff(val * 0.70710678f));
            if constexpr (RESID) val += resid[(size_t)row * N + col];
            if constexpr (OUTBF) outB[(size_t)row * N + col] = (bf16)val;
            else                 outF[(size_t)row * N + col] = val;
          }
        }
      }
  }
}

// ---------------- flash attention: 128 q-rows/block, KVBLK=128 -------------
// qt+1 barrier rounds. V^T chunk-XOR swizzled. (R20-proven, 1882.5 us)
__global__ __launch_bounds__(512) void fattn_kernel(
    const bf16* __restrict__ qkv, bf16* __restrict__ o) {
  constexpr int LP  = 72;    // Ks row stride (d-dim 64 + 8)
  constexpr int LPV = 136;   // Vt row stride (key-dim 128 + 8)
  constexpr int LPP = 136;   // Ps row stride (key-dim 128 + 8)
  constexpr int LDQ = 2304;
  __shared__ bf16 Ks[128 * LP];
  __shared__ bf16 Vt[64 * LPV];
  __shared__ bf16 Ps[8][16 * LPP];

  const int qt = 7 - (blockIdx.x & 7);          // descending work order
  const int hb = blockIdx.x >> 3;
  const int h  = hb % NH;
  const int b  = hb / NH;
  const int t = threadIdx.x;
  const int w = t >> 6, lane = t & 63;
  const int row16 = lane & 15, kg = lane >> 4;

  const bf16* kbase = qkv + 768  + (size_t)(b * SQ) * LDQ + h * 64;
  const bf16* vbase = qkv + 1536 + (size_t)(b * SQ) * LDQ + h * 64;

  const int wq0  = qt * 128 + w * 16;
  const int qrow = wq0 + row16;
  const bf16* qptr = qkv + (size_t)(b * SQ + qrow) * LDQ + h * 64;
  const bf16x8 qf0 = *(const bf16x8*)(qptr + kg * 8);
  const bf16x8 qf1 = *(const bf16x8*)(qptr + 32 + kg * 8);

  f32x4 oacc[4] = {};
  float mrow[4] = {-1e30f, -1e30f, -1e30f, -1e30f};
  float lrow[4] = {0.f, 0.f, 0.f, 0.f};
  const int myq = wq0 + kg * 4;
  const int ntiles = qt + 1;

  for (int jb0 = 0; jb0 < ntiles; jb0++) {
    const int j0 = jb0 * 128;
    __syncthreads();
    // ---- stage K [128][64] + V^T [64][128] (2 passes of 512 thr) ----
#pragma unroll
    for (int it = 0; it < 2; it++) {
      int idx = t + it * 512;
      int key = idx >> 3, d8 = (idx & 7) * 8;
      *(uint4*)(&Ks[key * LP + d8]) =
          *(const uint4*)(kbase + (size_t)(j0 + key) * LDQ + d8);
      bf16x8 vv = *(const bf16x8*)(vbase + (size_t)(j0 + key) * LDQ + d8);
      int kc = key >> 3, kl = key & 7;
#pragma unroll
      for (int e = 0; e < 8; e++) {
        int d = d8 + e;
        Vt[d * LPV + ((kc ^ (d >> 3)) << 3) + kl] = vv[e];
      }
    }
    __syncthreads();

    // ---- S = Q K^T (8 key-groups of 16) ----
    f32x4 sacc[8];
    __builtin_amdgcn_s_setprio(1);
#pragma unroll
    for (int jb = 0; jb < 8; jb++) {
      bf16x8 kf0 = *(const bf16x8*)(&Ks[(jb * 16 + row16) * LP + kg * 8]);
      bf16x8 kf1 = *(const bf16x8*)(&Ks[(jb * 16 + row16) * LP + 32 + kg * 8]);
      f32x4 sa = {};
      sa = __builtin_amdgcn_mfma_f32_16x16x32_bf16(qf0, kf0, sa, 0, 0, 0);
      sa = __builtin_amdgcn_mfma_f32_16x16x32_bf16(qf1, kf1, sa, 0, 0, 0);
      sacc[jb] = sa;
    }
    __builtin_amdgcn_s_setprio(0);

    constexpr float SC = 0.125f * 1.44269504f;
    if (j0 + 127 > wq0) {   // diagonal tile for this wave
#pragma unroll
      for (int jb = 0; jb < 8; jb++) {
        int keyg = j0 + jb * 16 + row16;
#pragma unroll
        for (int r = 0; r < 4; r++)
          sacc[jb][r] = (keyg <= myq + r) ? sacc[jb][r] * SC : -1e30f;
      }
    } else {
#pragma unroll
      for (int jb = 0; jb < 8; jb++)
#pragma unroll
        for (int r = 0; r < 4; r++)
          sacc[jb][r] *= SC;
    }

    // ---- online softmax (base-2) ----
    float p[8][4];
#pragma unroll
    for (int r = 0; r < 4; r++) {
      float mx = sacc[0][r];
#pragma unroll
      for (int jb = 1; jb < 8; jb++) mx = fmaxf(mx, sacc[jb][r]);
      mx = fmaxf(mx, __shfl_xor(mx, 1));
      mx = fmaxf(mx, __shfl_xor(mx, 2));
      mx = fmaxf(mx, __shfl_xor(mx, 4));
      mx = fmaxf(mx, __shfl_xor(mx, 8));
      float mn = fmaxf(mrow[r], mx);
      float al = exp2f(mrow[r] - mn);
      mrow[r] = mn;
      float ls = 0.f;
#pragma unroll
      for (int jb = 0; jb < 8; jb++) {
        float pv = exp2f(sacc[jb][r] - mn);
        p[jb][r] = pv;
        ls += pv;
      }
      ls += __shfl_xor(ls, 1);
      ls += __shfl_xor(ls, 2);
      ls += __shfl_xor(ls, 4);
      ls += __shfl_xor(ls, 8);
      lrow[r] = lrow[r] * al + ls;
#pragma unroll
      for (int dt = 0; dt < 4; dt++) oacc[dt][r] *= al;
    }

    // ---- P: C/D layout -> per-wave LDS -> A-fragment layout ----
    bf16* pw = &Ps[w][0];
#pragma unroll
    for (int jb = 0; jb < 8; jb++)
#pragma unroll
      for (int r = 0; r < 4; r++)
        pw[(kg * 4 + r) * LPP + jb * 16 + row16] = (bf16)p[jb][r];

    bf16x8 pf[4];
#pragma unroll
    for (int m = 0; m < 4; m++)
      pf[m] = *(const bf16x8*)(&pw[row16 * LPP + m * 32 + kg * 8]);

    // ---- O += P V (4 MFMA per dt over 128 keys) ----
    __builtin_amdgcn_s_setprio(1);
#pragma unroll
    for (int dt = 0; dt < 4; dt++) {
      int drow = dt * 16 + row16;
      int sw = drow >> 3;          // 0..7
#pragma unroll
      for (int m = 0; m < 4; m++) {
        bf16x8 vf = *(const bf16x8*)(&Vt[drow * LPV + (((m * 4 + kg) ^ sw) << 3)]);
        oacc[dt] = __builtin_amdgcn_mfma_f32_16x16x32_bf16(pf[m], vf, oacc[dt], 0, 0, 0);
      }
    }
    __builtin_amdgcn_s_setprio(0);
  }

  bf16* obase = o + (size_t)(b * SQ + wq0 + kg * 4) * DIM + h * 64;
#pragma unroll
  for (int r = 0; r < 4; r++) {
    float inv = 1.0f / lrow[r];
#pragma unroll
    for (int dt = 0; dt < 4; dt++)
      obase[(size_t)r * DIM + dt * 16 + row16] = (bf16)(oacc[dt][r] * inv);
  }
}

// ---------------------------------------------------------------------------
extern "C" void kernel_launch(void* const* d_in, const int* in_sizes, int n_in,
                              void* d_out, int out_size, void* d_ws, size_t ws_size,
                              hipStream_t stream) {
  const int*   tokens  = (const int*)  d_in[0];
  const float* tok_emb = (const float*)d_in[1];
  const float* pos_emb = (const float*)d_in[2];
  const float* ln1_g   = (const float*)d_in[3];
  const float* ln1_b   = (const float*)d_in[4];
  const float* wq      = (const float*)d_in[5];
  const float* bq      = (const float*)d_in[6];
  const float* wk      = (const float*)d_in[7];
  const float* bk      = (const float*)d_in[8];
  const float* wv      = (const float*)d_in[9];
  const float* bv      = (const float*)d_in[10];
  const float* wo      = (const float*)d_in[11];
  const float* bo      = (const float*)d_in[12];
  const float* ln2_g   = (const float*)d_in[13];
  const float* ln2_b   = (const float*)d_in[14];
  const float* w1      = (const float*)d_in[15];
  const float* b1      = (const float*)d_in[16];
  const float* w2      = (const float*)d_in[17];
  const float* b2      = (const float*)d_in[18];
  const float* fn_g    = (const float*)d_in[19];
  const float* fn_b    = (const float*)d_in[20];
  const float* head_w  = (const float*)d_in[21];
  const float* head_b  = (const float*)d_in[22];
  float* out = (float*)d_out;

  const int ROWS = 2 * SQ;  // 2048
  char* p = (char*)d_ws;
  float* x   = (float*)p;  p += (size_t)ROWS * DIM * 4;
  bf16*  h   = (bf16*)p;   p += (size_t)ROWS * DIM * 2;
  bf16*  qkv = (bf16*)p;   p += (size_t)ROWS * 2304 * 2;
  bf16*  ao  = (bf16*)p;   p += (size_t)ROWS * DIM * 2;
  bf16*  mid = (bf16*)p;   p += (size_t)ROWS * F4  * 2;
  bf16*  WqkvT = (bf16*)p; p += (size_t)NL * 2304 * DIM * 2;
  bf16*  WoT   = (bf16*)p; p += (size_t)NL * DIM * DIM * 2;
  bf16*  W1T   = (bf16*)p; p += (size_t)NL * F4 * DIM * 2;
  bf16*  W2T   = (bf16*)p; p += (size_t)NL * DIM * F4 * 2;
  bf16*  WhT   = (bf16*)p; p += (size_t)NPADV * DIM * 2;
  float* qkvb  = (float*)p; p += (size_t)NL * 2304 * 4;

  embed_kernel<<<ROWS, 256, 0, stream>>>(tokens, tok_emb, pos_emb, x);

  {
    dim3 gdd(DIM / 32, DIM / 32, NL);
    size_t ss = (size_t)DIM * DIM, ds = (size_t)2304 * DIM;
    tconv_kernel<<<gdd, 256, 0, stream>>>(wq, WqkvT,                       DIM, DIM, ss, ds);
    tconv_kernel<<<gdd, 256, 0, stream>>>(wk, WqkvT + (size_t)768  * DIM,  DIM, DIM, ss, ds);
    tconv_kernel<<<gdd, 256, 0, stream>>>(wv, WqkvT + (size_t)1536 * DIM,  DIM, DIM, ss, ds);
    tconv_kernel<<<gdd, 256, 0, stream>>>(wo, WoT, DIM, DIM, ss, ss);
    dim3 g1(F4 / 32, DIM / 32, NL);
    tconv_kernel<<<g1, 256, 0, stream>>>(w1, W1T, DIM, F4, (size_t)DIM * F4, (size_t)F4 * DIM);
    dim3 g2(DIM / 32, F4 / 32, NL);
    tconv_kernel<<<g2, 256, 0, stream>>>(w2, W2T, F4, DIM, (size_t)F4 * DIM, (size_t)DIM * F4);
    dim3 gh(NPADV / 32, DIM / 32, 1);
    tconv_kernel<<<gh, 256, 0, stream>>>(head_w, WhT, DIM, NVOC, 0, 0);
    packb_kernel<<<NL, 256, 0, stream>>>(bq, bk, bv, qkvb);
  }

  dim3 gQKV(32, 2304 / 128);   // 576
  dim3 gD(32, DIM / 128);      // 192
  dim3 gF(32, F4 / 128);       // 768
  dim3 gV(16, NPADV / 128);    // 6288

  for (int l = 0; l < NL; l++) {
    ln_kernel<<<ROWS, 256, 0, stream>>>(x, ln1_g + l * DIM, ln1_b + l * DIM, h);
    gemm_bt<64, 2, false, false, true, false><<<gQKV, 256, 0, stream>>>(
        h, WqkvT + (size_t)l * 2304 * DIM, qkvb + (size_t)l * 2304,
        nullptr, nullptr, qkv, ROWS, 2304, DIM);
    fattn_kernel<<<2 * NH * (SQ / 128), 512, 0, stream>>>(qkv, ao);
    gemm_bt<64, 3, false, true, false, false><<<gD, 256, 0, stream>>>(
        ao, WoT + (size_t)l * DIM * DIM, bo + l * DIM, x, x, nullptr, ROWS, DIM, DIM);
    ln_kernel<<<ROWS, 256, 0, stream>>>(x, ln2_g + l * DIM, ln2_b + l * DIM, h);
    gemm_bt<64, 2, true, false, true, false><<<gF, 256, 0, stream>>>(
        h, W1T + (size_t)l * F4 * DIM, b1 + l * F4, nullptr, nullptr, mid, ROWS, F4, DIM);
    gemm_bt<64, 3, false, true, false, false><<<gD, 256, 0, stream>>>(
        mid, W2T + (size_t)l * DIM * F4, b2 + l * DIM, x, x, nullptr, ROWS, DIM, F4);
  }
  ln_kernel<<<ROWS, 256, 0, stream>>>(x, fn_g, fn_b, h);
  gemm_bt<128, 2, false, false, false, true><<<gV, 512, 0, stream>>>(
      h, WhT, head_b, nullptr, out, nullptr, ROWS, NVOC, DIM);
}